// Round 7
// baseline (225.406 us; speedup 1.0000x reference)
//
#include <hip/hip_runtime.h>
#include <math.h>

#define BATCH 8
#define SEQ 2048
#define DIM 128
#define SCALE 0.08838834764831845f  // 1/sqrt(128)
#define NEGINF (-1e30f)
#define PSTR 40
#define INVSEQ (1.0f / 2048.0f)

// workspace byte offsets
#define OFF_VSUM 0                        // 8*128 f32 = 4 KB (atomically accumulated)
#define OFF_KW   4096                     // 4 MB frag-major bf16 K*SCALE
#define OFF_VW   (4096 + 4194304)         // 4 MB frag-major bf16 V^T
#define WS_NEEDED (4096 + 2 * 4194304)

typedef __attribute__((ext_vector_type(8))) short short8;
typedef __attribute__((ext_vector_type(4))) float floatx4;

union U8 { unsigned u[4]; short8 s; uint4 q; };

// pack two f32 -> bf16 pair (round-half-up): low16 = bf16(f0), high16 = bf16(f1)
__device__ __forceinline__ unsigned pk_bf(float f0, float f1) {
    unsigned a = __float_as_uint(f0) + 0x8000u;
    unsigned b = __float_as_uint(f1) + 0x8000u;
    return __builtin_amdgcn_perm(a, b, 0x03020706u);
}

// =================== conv3: coalesced frag-major converter ===================
// blocks 0..511: K tiles (32 keys). blocks 512..1023: V tiles (+ vmean atomics).
// kw record f=nt*4+ds: lane(quad*16+l16) 16B = K[tile*32+nt*16+l16][ds*32+quad*8..+8]*SCALE
// vw record dt:        lane(quad*16+l16) 16B = V^T: keys quad*8..+8 at d=dt*16+l16
__global__ __launch_bounds__(256) void conv3(const float* __restrict__ k,
                                             const float* __restrict__ v,
                                             unsigned short* __restrict__ kw,
                                             unsigned short* __restrict__ vw,
                                             float* __restrict__ vsum) {
    __shared__ __align__(16) unsigned sL[2176];   // K: 32x66 dwords; V: 128x17 dwords
    int blk = blockIdx.x, t = threadIdx.x;
    if (blk < 512) {
        int b = blk >> 6, tile = blk & 63;
        const float4* src = (const float4*)(k + ((size_t)(b * SEQ + tile * 32)) * DIM);
        #pragma unroll
        for (int i = 0; i < 4; ++i) {            // coalesced: lane-contiguous float4
            int F = t + 256 * i;
            int r = F >> 5, c4 = F & 31;
            float4 x = src[F];
            uint2 p;
            p.x = pk_bf(x.x * SCALE, x.y * SCALE);
            p.y = pk_bf(x.z * SCALE, x.w * SCALE);
            *(uint2*)&sL[r * 66 + c4 * 2] = p;   // b64, ~4-way banks
        }
        __syncthreads();
        uint4* dst = (uint4*)(kw + (size_t)(b * 64 + tile) * 4096);
        #pragma unroll
        for (int si = 0; si < 2; ++si) {         // frag-order read, coalesced store
            int s = 2 * t + si;
            int f = s >> 6, ln = s & 63;
            int l16 = ln & 15, quad = ln >> 4;
            int nt = f >> 2, ds = f & 3;
            int base = (nt * 16 + l16) * 66 + ds * 16 + quad * 4;
            uint2 a = *(const uint2*)&sL[base];
            uint2 c = *(const uint2*)&sL[base + 2];
            dst[s] = make_uint4(a.x, a.y, c.x, c.y);
        }
    } else {
        int blk2 = blk - 512;
        int b = blk2 >> 6, tile = blk2 & 63;
        const float4* src = (const float4*)(v + ((size_t)(b * SEQ + tile * 32)) * DIM);
        #pragma unroll
        for (int h = 0; h < 2; ++h) {            // key-pair transpose, coalesced loads
            int kp = (t >> 5) + 8 * h;           // key-pair 0..15
            int c4 = t & 31;
            float4 x0 = src[(2 * kp) * 32 + c4];
            float4 x1 = src[(2 * kp + 1) * 32 + c4];
            int d0 = c4 * 4;
            sL[(d0 + 0) * 17 + kp] = pk_bf(x0.x, x1.x);   // low=key 2kp, high=2kp+1
            sL[(d0 + 1) * 17 + kp] = pk_bf(x0.y, x1.y);
            sL[(d0 + 2) * 17 + kp] = pk_bf(x0.z, x1.z);
            sL[(d0 + 3) * 17 + kp] = pk_bf(x0.w, x1.w);
        }
        __syncthreads();
        uint4* dst = (uint4*)(vw + (size_t)(b * 64 + tile) * 4096);
        #pragma unroll
        for (int si = 0; si < 2; ++si) {
            int s = 2 * t + si;
            int dt = s >> 6, ln = s & 63;
            int l16 = ln & 15, quad = ln >> 4;
            int base = (dt * 16 + l16) * 17 + quad * 4;
            dst[s] = make_uint4(sL[base], sL[base + 1], sL[base + 2], sL[base + 3]);
        }
        if (t < 128) {                           // per-tile vmean partial, 1 atomic/dim
            float ssum = 0.f;
            #pragma unroll
            for (int j = 0; j < 16; ++j) {
                unsigned u = sL[t * 17 + j];
                ssum += __uint_as_float(u << 16);
                ssum += __uint_as_float(u & 0xffff0000u);
            }
            atomicAdd(&vsum[b * DIM + t], ssum);
        }
    }
}

// =================== attn8: 8 key-slices + K double-buffer ===================
// Block = 512 thr = 8 waves = 1 q-tile (16 rows) x 8 key-slices. Grid = 8*128.
// S^T = K.Q^T (scale folded into K); O^T = V^T.P^T; per-lane softmax stats.
#define LOADK(kb_, KF_)                                                        \
    {                                                                          \
        const unsigned short* kT_ = kwB + (size_t)((kb_) >> 5) * 4096 + lane * 8; \
        _Pragma("unroll")                                                      \
        for (int f_ = 0; f_ < 8; ++f_) KF_[f_] = *(const short8*)(kT_ + f_ * 512); \
    }

#define CHUNK(KF_, kb_)                                                        \
    {                                                                          \
        floatx4 S0 = (floatx4){0.f, 0.f, 0.f, 0.f};                            \
        floatx4 S1 = (floatx4){0.f, 0.f, 0.f, 0.f};                            \
        _Pragma("unroll")                                                      \
        for (int ds = 0; ds < 4; ++ds)                                         \
            S0 = __builtin_amdgcn_mfma_f32_16x16x32_bf16(KF_[ds], Qf[ds], S0, 0, 0, 0); \
        _Pragma("unroll")                                                      \
        for (int ds = 0; ds < 4; ++ds)                                         \
            S1 = __builtin_amdgcn_mfma_f32_16x16x32_bf16(KF_[4 + ds], Qf[ds], S1, 0, 0, 0); \
        short8 VF[8];                                                          \
        {                                                                      \
            const unsigned short* vT_ = vwB + (size_t)((kb_) >> 5) * 4096 + lane * 8; \
            _Pragma("unroll")                                                  \
            for (int dt = 0; dt < 8; ++dt) VF[dt] = *(const short8*)(vT_ + dt * 512); \
        }                                                                      \
        PREFETCH_NEXT                                                          \
        int kl0 = (kb_) + quad * 4;                                            \
        int kl1 = kl0 + 16;                                                    \
        float s0v[4], s1v[4];                                                  \
        float mt = m;                                                          \
        _Pragma("unroll")                                                      \
        for (int r = 0; r < 4; ++r) {                                          \
            s0v[r] = (kl0 + r < kend) ? S0[r] : NEGINF;                        \
            s1v[r] = (kl1 + r < kend) ? S1[r] : NEGINF;                        \
            mt = fmaxf(mt, fmaxf(s0v[r], s1v[r]));                             \
        }                                                                      \
        mt = fmaxf(mt, __shfl_xor(mt, 16));                                    \
        mt = fmaxf(mt, __shfl_xor(mt, 32));                                    \
        float alpha = __expf(m - mt);                                          \
        m = mt;                                                                \
        float p0[4], p1[4], ps = 0.f;                                          \
        _Pragma("unroll")                                                      \
        for (int r = 0; r < 4; ++r) {                                          \
            p0[r] = __expf(s0v[r] - mt);                                       \
            p1[r] = __expf(s1v[r] - mt);                                       \
            ps += p0[r] + p1[r];                                               \
        }                                                                      \
        ps += __shfl_xor(ps, 16);                                              \
        ps += __shfl_xor(ps, 32);                                              \
        l = l * alpha + ps;                                                    \
        _Pragma("unroll")                                                      \
        for (int dt = 0; dt < 8; ++dt) {                                       \
            _Pragma("unroll")                                                  \
            for (int r = 0; r < 4; ++r) O[dt][r] *= alpha;                     \
        }                                                                      \
        {                                                                      \
            uint2 w0, w1;                                                      \
            w0.x = pk_bf(p0[0], p0[1]); w0.y = pk_bf(p0[2], p0[3]);            \
            w1.x = pk_bf(p1[0], p1[1]); w1.y = pk_bf(p1[2], p1[3]);            \
            *(uint2*)&sPw[l16 * PSTR + quad * 4]      = w0;                    \
            *(uint2*)&sPw[l16 * PSTR + 16 + quad * 4] = w1;                    \
        }                                                                      \
        short8 Pf = *(const short8*)&sPw[l16 * PSTR + quad * 8];               \
        _Pragma("unroll")                                                      \
        for (int dt = 0; dt < 8; ++dt)                                         \
            O[dt] = __builtin_amdgcn_mfma_f32_16x16x32_bf16(VF[dt], Pf, O[dt], 0, 0, 0); \
    }

__global__ __launch_bounds__(512, 4) void attn8(const float* __restrict__ q,
                                                const unsigned short* __restrict__ kw,
                                                const unsigned short* __restrict__ vw,
                                                const int* __restrict__ lens,
                                                const float* __restrict__ vsum,
                                                float* __restrict__ out) {
    __shared__ __align__(16) unsigned short sP[8][16 * PSTR];  // 10240 B
    __shared__ float sC[7][16][132];                           // 59136 B
    __shared__ float sS[8][16][2];                             //  1024 B

    int blk = blockIdx.x;
    int b = blk & 7;
    int q0 = (blk >> 3) * 16;
    int len = lens[b];
    int t = threadIdx.x;
    int lane = t & 63;
    int ks = t >> 6;                 // key-slice 0..7
    int l16 = lane & 15;
    int quad = lane >> 4;
    const int bo = b * SEQ * DIM;

    if (q0 >= len) {                 // block-uniform early exit: vmean rows
        int row = t >> 5;
        int c0 = (t & 31) * 4;
        float4 a = *(const float4*)&vsum[b * DIM + c0];
        *(float4*)(out + bo + (q0 + row) * DIM + c0) =
            make_float4(a.x * INVSEQ, a.y * INVSEQ, a.z * INVSEQ, a.w * INVSEQ);
        return;
    }

    int slice = ((len + 255) >> 8) << 5;   // 32-aligned per-wave key range
    int kbeg = ks * slice;
    int kend = min(kbeg + slice, len);

    floatx4 O[8];
    #pragma unroll
    for (int dt = 0; dt < 8; ++dt) O[dt] = (floatx4){0.f, 0.f, 0.f, 0.f};
    float m = NEGINF, l = 0.f;
    unsigned short* sPw = sP[ks];
    const unsigned short* kwB = kw + (size_t)b * 64 * 4096;
    const unsigned short* vwB = vw + (size_t)b * 64 * 4096;

    if (kbeg < kend) {
        short8 Qf[4];                // Q B-frags: B[k=d][n=qrow=l16]
        {
            const float* qp = q + bo + (q0 + l16) * DIM + quad * 8;
            #pragma unroll
            for (int ds = 0; ds < 4; ++ds) {
                float4 x0 = *(const float4*)(qp + ds * 32);
                float4 x1 = *(const float4*)(qp + ds * 32 + 4);
                U8 f;
                f.u[0] = pk_bf(x0.x, x0.y); f.u[1] = pk_bf(x0.z, x0.w);
                f.u[2] = pk_bf(x1.x, x1.y); f.u[3] = pk_bf(x1.z, x1.w);
                Qf[ds] = f.s;
            }
        }

        short8 KA[8], KB[8];
        LOADK(kbeg, KA)
        int kb = kbeg;
        while (true) {
#define PREFETCH_NEXT if (kb + 32 < kend) LOADK(kb + 32, KB)
            CHUNK(KA, kb)
#undef PREFETCH_NEXT
            kb += 32;
            if (kb >= kend) break;
#define PREFETCH_NEXT if (kb + 32 < kend) LOADK(kb + 32, KA)
            CHUNK(KB, kb)
#undef PREFETCH_NEXT
            kb += 32;
            if (kb >= kend) break;
        }
    }

    // ---- cross-slice combine (one barrier) ----
    if (ks > 0) {
        if (quad == 0) { sS[ks][l16][0] = m; sS[ks][l16][1] = l; }
        #pragma unroll
        for (int dt = 0; dt < 8; ++dt)
            *(floatx4*)&sC[ks - 1][l16][dt * 16 + quad * 4] = O[dt];
    }
    __syncthreads();

    if (ks == 0) {
        float mw[7], lw[7];
        float mstar = m;
        #pragma unroll
        for (int w = 0; w < 7; ++w) {
            mw[w] = sS[w + 1][l16][0];
            lw[w] = sS[w + 1][l16][1];
            mstar = fmaxf(mstar, mw[w]);
        }
        float s0 = __expf(m - mstar);
        float sw[7];
        float lstar = s0 * l;
        #pragma unroll
        for (int w = 0; w < 7; ++w) {
            sw[w] = __expf(mw[w] - mstar);
            lstar += sw[w] * lw[w];
        }
        float inv = 1.f / lstar;
        bool rowvalid = (q0 + l16) < len;
        float* ob = out + bo + (q0 + l16) * DIM;
        const float* vm = vsum + b * DIM;
        #pragma unroll
        for (int dt = 0; dt < 8; ++dt) {
            floatx4 acc = O[dt];
            #pragma unroll
            for (int r = 0; r < 4; ++r) acc[r] *= s0;
            #pragma unroll
            for (int w = 0; w < 7; ++w) {
                floatx4 ow = *(const floatx4*)&sC[w][l16][dt * 16 + quad * 4];
                #pragma unroll
                for (int r = 0; r < 4; ++r) acc[r] += sw[w] * ow[r];
            }
            float4 res;
            if (rowvalid) {
                res = make_float4(acc[0] * inv, acc[1] * inv, acc[2] * inv, acc[3] * inv);
            } else {
                float4 vv = *(const float4*)(vm + dt * 16 + quad * 4);
                res = make_float4(vv.x * INVSEQ, vv.y * INVSEQ, vv.z * INVSEQ, vv.w * INVSEQ);
            }
            *(float4*)(ob + dt * 16 + quad * 4) = res;
        }
    }
}

// =================== fallback path (ws too small): R3 kernel ===================
__global__ __launch_bounds__(256) void vmean_partial(const float* __restrict__ v,
                                                     float* __restrict__ part) {
    int blk = blockIdx.x;
    int b = blk >> 3, oct = blk & 7;
    int t = threadIdx.x;
    int d4 = t & 31, rg = t >> 5;
    const float4* vb = (const float4*)(v + (size_t)b * SEQ * DIM);
    float4 acc = make_float4(0.f, 0.f, 0.f, 0.f);
    int base = oct * 256 + rg * 32;
    #pragma unroll 8
    for (int i = 0; i < 32; ++i) {
        float4 x = vb[(size_t)(base + i) * 32 + d4];
        acc.x += x.x; acc.y += x.y; acc.z += x.z; acc.w += x.w;
    }
    __shared__ float4 red[8][32];
    red[rg][d4] = acc;
    __syncthreads();
    if (t < 32) {
        float4 s = red[0][t];
        #pragma unroll
        for (int r = 1; r < 8; ++r) {
            float4 x = red[r][t];
            s.x += x.x; s.y += x.y; s.z += x.z; s.w += x.w;
        }
        ((float4*)part)[(size_t)blk * 32 + t] = s;
    }
}

__global__ __launch_bounds__(128) void vmean_combine(const float* __restrict__ part,
                                                     float* __restrict__ vmean) {
    int b = blockIdx.x, t = threadIdx.x;
    float s = 0.f;
    #pragma unroll
    for (int o = 0; o < 8; ++o) s += part[((size_t)b * 8 + o) * DIM + t];
    vmean[b * DIM + t] = s * INVSEQ;
}

__global__ __launch_bounds__(512, 4) void attn_flash(const float* __restrict__ q,
                                                     const float* __restrict__ k,
                                                     const float* __restrict__ v,
                                                     const int* __restrict__ lens,
                                                     const float* __restrict__ vmean,
                                                     float* __restrict__ out) {
    __shared__ unsigned short sPf[8 * 16 * PSTR];
    __shared__ float sC[2][3][16][132];
    __shared__ float sS[2][4][16][2];

    int blk = blockIdx.x;
    int b = blk & 7;
    int g = blk >> 3;
    int q0 = g * 32;
    int len = lens[b];
    int t = threadIdx.x;
    int lane = t & 63;
    int wave = t >> 6;
    int qt = wave & 1;
    int ks = wave >> 1;
    int l16 = lane & 15;
    int quad = lane >> 4;
    const int bo = b * SEQ * DIM;

    int rowbase = q0 + qt * 16;
    bool active = q0 < len;

    int slice = (len + 3) >> 2;
    int kbeg = ks * slice;
    int kend = min(kbeg + slice, len);

    floatx4 O[8];
    #pragma unroll
    for (int dt = 0; dt < 8; ++dt) O[dt] = (floatx4){0.f, 0.f, 0.f, 0.f};
    float m = NEGINF, l = 0.f;
    unsigned short* sPw = &sPf[wave * 16 * PSTR];

    if (active && kbeg < kend) {
        short8 Qf[4];
        {
            const float* qp = q + bo + (rowbase + l16) * DIM + quad * 8;
            #pragma unroll
            for (int ds = 0; ds < 4; ++ds) {
                float4 x0 = *(const float4*)(qp + ds * 32);
                float4 x1 = *(const float4*)(qp + ds * 32 + 4);
                U8 f;
                f.u[0] = pk_bf(x0.x, x0.y); f.u[1] = pk_bf(x0.z, x0.w);
                f.u[2] = pk_bf(x1.x, x1.y); f.u[3] = pk_bf(x1.z, x1.w);
                Qf[ds] = f.s;
            }
        }
        for (int kb = kbeg; kb < kend; kb += 32) {
            int kr0 = kb + l16;      kr0 = kr0 < SEQ ? kr0 : SEQ - 1;
            int kr1 = kb + 16 + l16; kr1 = kr1 < SEQ ? kr1 : SEQ - 1;
            const float* kp0 = k + bo + kr0 * DIM + quad * 8;
            const float* kp1 = k + bo + kr1 * DIM + quad * 8;
            floatx4 S0 = (floatx4){0.f, 0.f, 0.f, 0.f};
            floatx4 S1 = (floatx4){0.f, 0.f, 0.f, 0.f};
            #pragma unroll
            for (int ds = 0; ds < 4; ++ds) {
                float4 a0 = *(const float4*)(kp0 + ds * 32);
                float4 a1 = *(const float4*)(kp0 + ds * 32 + 4);
                U8 f;
                f.u[0] = pk_bf(a0.x, a0.y); f.u[1] = pk_bf(a0.z, a0.w);
                f.u[2] = pk_bf(a1.x, a1.y); f.u[3] = pk_bf(a1.z, a1.w);
                S0 = __builtin_amdgcn_mfma_f32_16x16x32_bf16(f.s, Qf[ds], S0, 0, 0, 0);
            }
            #pragma unroll
            for (int ds = 0; ds < 4; ++ds) {
                float4 a0 = *(const float4*)(kp1 + ds * 32);
                float4 a1 = *(const float4*)(kp1 + ds * 32 + 4);
                U8 f;
                f.u[0] = pk_bf(a0.x, a0.y); f.u[1] = pk_bf(a0.z, a0.w);
                f.u[2] = pk_bf(a1.x, a1.y); f.u[3] = pk_bf(a1.z, a1.w);
                S1 = __builtin_amdgcn_mfma_f32_16x16x32_bf16(f.s, Qf[ds], S1, 0, 0, 0);
            }
            int kl0 = kb + quad * 4;
            int kl1 = kb + 16 + quad * 4;
            float s0v[4], s1v[4];
            float mt = m;
            #pragma unroll
            for (int r = 0; r < 4; ++r) {
                s0v[r] = (kl0 + r < kend) ? S0[r] * SCALE : NEGINF;
                s1v[r] = (kl1 + r < kend) ? S1[r] * SCALE : NEGINF;
                mt = fmaxf(mt, fmaxf(s0v[r], s1v[r]));
            }
            mt = fmaxf(mt, __shfl_xor(mt, 16));
            mt = fmaxf(mt, __shfl_xor(mt, 32));
            float alpha = __expf(m - mt);
            m = mt;
            float p0[4], p1[4], ps = 0.f;
            #pragma unroll
            for (int r = 0; r < 4; ++r) {
                p0[r] = __expf(s0v[r] - mt);
                p1[r] = __expf(s1v[r] - mt);
                ps += p0[r] + p1[r];
            }
            ps += __shfl_xor(ps, 16);
            ps += __shfl_xor(ps, 32);
            l = l * alpha + ps;
            #pragma unroll
            for (int dt = 0; dt < 8; ++dt) {
                #pragma unroll
                for (int r = 0; r < 4; ++r) O[dt][r] *= alpha;
            }
            {
                uint2 w0, w1;
                w0.x = pk_bf(p0[0], p0[1]); w0.y = pk_bf(p0[2], p0[3]);
                w1.x = pk_bf(p1[0], p1[1]); w1.y = pk_bf(p1[2], p1[3]);
                *(uint2*)&sPw[l16 * PSTR + quad * 4]      = w0;
                *(uint2*)&sPw[l16 * PSTR + 16 + quad * 4] = w1;
            }
            short8 Pf = *(const short8*)&sPw[l16 * PSTR + quad * 8];
            int vro[8];
            #pragma unroll
            for (int jj = 0; jj < 8; ++jj) {
                int kk = kb + quad * 8 + jj;
                kk = kk < SEQ ? kk : SEQ - 1;
                vro[jj] = kk * DIM;
            }
            const float* vb = v + bo + l16;
            #pragma unroll
            for (int dt = 0; dt < 8; ++dt) {
                int c = dt * 16;
                float x0 = vb[vro[0] + c], x1 = vb[vro[1] + c];
                float x2 = vb[vro[2] + c], x3 = vb[vro[3] + c];
                float x4 = vb[vro[4] + c], x5 = vb[vro[5] + c];
                float x6 = vb[vro[6] + c], x7 = vb[vro[7] + c];
                U8 f;
                f.u[0] = pk_bf(x0, x1); f.u[1] = pk_bf(x2, x3);
                f.u[2] = pk_bf(x4, x5); f.u[3] = pk_bf(x6, x7);
                O[dt] = __builtin_amdgcn_mfma_f32_16x16x32_bf16(f.s, Pf, O[dt], 0, 0, 0);
            }
        }
    }

    if (active && ks > 0) {
        if (quad == 0) { sS[qt][ks][l16][0] = m; sS[qt][ks][l16][1] = l; }
        #pragma unroll
        for (int dt = 0; dt < 8; ++dt)
            *(floatx4*)&sC[qt][ks - 1][l16][dt * 16 + quad * 4] = O[dt];
    }
    __syncthreads();

    if (ks == 0) {
        const float* vm = vmean + b * DIM;
        float* ob = out + bo + (rowbase + l16) * DIM;
        if (active) {
            float mw[3], lw[3];
            float mstar = m;
            #pragma unroll
            for (int w = 0; w < 3; ++w) {
                mw[w] = sS[qt][w + 1][l16][0];
                lw[w] = sS[qt][w + 1][l16][1];
                mstar = fmaxf(mstar, mw[w]);
            }
            float s0 = __expf(m - mstar);
            float sw[3];
            float lstar = s0 * l;
            #pragma unroll
            for (int w = 0; w < 3; ++w) {
                sw[w] = __expf(mw[w] - mstar);
                lstar += sw[w] * lw[w];
            }
            float inv = 1.f / lstar;
            bool rowvalid = (rowbase + l16) < len;
            #pragma unroll
            for (int dt = 0; dt < 8; ++dt) {
                floatx4 acc = O[dt];
                #pragma unroll
                for (int r = 0; r < 4; ++r) acc[r] *= s0;
                #pragma unroll
                for (int w = 0; w < 3; ++w) {
                    floatx4 ow = *(const floatx4*)&sC[qt][w][l16][dt * 16 + quad * 4];
                    #pragma unroll
                    for (int r = 0; r < 4; ++r) acc[r] += sw[w] * ow[r];
                }
                float4 res;
                if (rowvalid) {
                    res = make_float4(acc[0] * inv, acc[1] * inv, acc[2] * inv, acc[3] * inv);
                } else {
                    res = *(const float4*)(vm + dt * 16 + quad * 4);
                }
                *(float4*)(ob + dt * 16 + quad * 4) = res;
            }
        } else {
            #pragma unroll
            for (int dt = 0; dt < 8; ++dt)
                *(float4*)(ob + dt * 16 + quad * 4) =
                    *(const float4*)(vm + dt * 16 + quad * 4);
        }
    }
}

extern "C" void kernel_launch(void* const* d_in, const int* in_sizes, int n_in,
                              void* d_out, int out_size, void* d_ws, size_t ws_size,
                              hipStream_t stream) {
    const float* q = (const float*)d_in[0];
    const float* k = (const float*)d_in[1];
    const float* v = (const float*)d_in[2];
    const int* lens = (const int*)d_in[3];
    float* out = (float*)d_out;

    if (ws_size >= (size_t)WS_NEEDED) {
        float* vsum = (float*)((char*)d_ws + OFF_VSUM);
        unsigned short* kw = (unsigned short*)((char*)d_ws + OFF_KW);
        unsigned short* vw = (unsigned short*)((char*)d_ws + OFF_VW);
        hipMemsetAsync(vsum, 0, BATCH * DIM * sizeof(float), stream);
        conv3<<<dim3(1024), dim3(256), 0, stream>>>(k, v, kw, vw, vsum);
        attn8<<<dim3(1024), dim3(512), 0, stream>>>(q, kw, vw, lens, vsum, out);
    } else {
        float* part = (float*)d_ws;
        float* vmean = part + 64 * DIM;
        vmean_partial<<<dim3(64), dim3(256), 0, stream>>>(v, part);
        vmean_combine<<<dim3(8), dim3(128), 0, stream>>>(part, vmean);
        attn_flash<<<dim3(512), dim3(512), 0, stream>>>(q, k, v, lens, vmean, out);
    }
}

// Round 8
// 116.191 us; speedup vs baseline: 1.9400x; 1.9400x over previous
//
#include <hip/hip_runtime.h>
#include <math.h>

#define BATCH 8
#define SEQ 2048
#define DIM 128
#define SCALE 0.08838834764831845f  // 1/sqrt(128)
#define NEGINF (-1e30f)
#define PSTR 40
#define INVSEQ (1.0f / 2048.0f)

// workspace byte offsets
#define OFF_VSUM 0                        // 8*128 f32 = 4 KB (atomically accumulated)
#define OFF_KW   4096                     // 4 MB frag-major bf16 K*SCALE
#define OFF_VW   (4096 + 4194304)         // 4 MB frag-major bf16 V^T
#define WS_NEEDED (4096 + 2 * 4194304)

typedef __attribute__((ext_vector_type(8))) short short8;
typedef __attribute__((ext_vector_type(4))) float floatx4;

union U8 { unsigned u[4]; short8 s; uint4 q; };

// pack two f32 -> bf16 pair (round-half-up): low16 = bf16(f0), high16 = bf16(f1)
__device__ __forceinline__ unsigned pk_bf(float f0, float f1) {
    unsigned a = __float_as_uint(f0) + 0x8000u;
    unsigned b = __float_as_uint(f1) + 0x8000u;
    return __builtin_amdgcn_perm(a, b, 0x03020706u);
}

// =================== conv3: coalesced frag-major converter ===================
// blocks 0..511: K tiles (32 keys). blocks 512..1023: V tiles (+ vmean atomics).
__global__ __launch_bounds__(256) void conv3(const float* __restrict__ k,
                                             const float* __restrict__ v,
                                             unsigned short* __restrict__ kw,
                                             unsigned short* __restrict__ vw,
                                             float* __restrict__ vsum) {
    __shared__ __align__(16) unsigned sL[2176];   // K: 32x66 dwords; V: 128x17 dwords
    int blk = blockIdx.x, t = threadIdx.x;
    if (blk < 512) {
        int b = blk >> 6, tile = blk & 63;
        const float4* src = (const float4*)(k + ((size_t)(b * SEQ + tile * 32)) * DIM);
        #pragma unroll
        for (int i = 0; i < 4; ++i) {            // coalesced: lane-contiguous float4
            int F = t + 256 * i;
            int r = F >> 5, c4 = F & 31;
            float4 x = src[F];
            uint2 p;
            p.x = pk_bf(x.x * SCALE, x.y * SCALE);
            p.y = pk_bf(x.z * SCALE, x.w * SCALE);
            *(uint2*)&sL[r * 66 + c4 * 2] = p;
        }
        __syncthreads();
        uint4* dst = (uint4*)(kw + (size_t)(b * 64 + tile) * 4096);
        #pragma unroll
        for (int si = 0; si < 2; ++si) {         // frag-order read, coalesced store
            int s = 2 * t + si;
            int f = s >> 6, ln = s & 63;
            int l16 = ln & 15, quad = ln >> 4;
            int nt = f >> 2, ds = f & 3;
            int base = (nt * 16 + l16) * 66 + ds * 16 + quad * 4;
            uint2 a = *(const uint2*)&sL[base];
            uint2 c = *(const uint2*)&sL[base + 2];
            dst[s] = make_uint4(a.x, a.y, c.x, c.y);
        }
    } else {
        int blk2 = blk - 512;
        int b = blk2 >> 6, tile = blk2 & 63;
        const float4* src = (const float4*)(v + ((size_t)(b * SEQ + tile * 32)) * DIM);
        #pragma unroll
        for (int h = 0; h < 2; ++h) {            // key-pair transpose, coalesced loads
            int kp = (t >> 5) + 8 * h;           // key-pair 0..15
            int c4 = t & 31;
            float4 x0 = src[(2 * kp) * 32 + c4];
            float4 x1 = src[(2 * kp + 1) * 32 + c4];
            int d0 = c4 * 4;
            sL[(d0 + 0) * 17 + kp] = pk_bf(x0.x, x1.x);
            sL[(d0 + 1) * 17 + kp] = pk_bf(x0.y, x1.y);
            sL[(d0 + 2) * 17 + kp] = pk_bf(x0.z, x1.z);
            sL[(d0 + 3) * 17 + kp] = pk_bf(x0.w, x1.w);
        }
        __syncthreads();
        uint4* dst = (uint4*)(vw + (size_t)(b * 64 + tile) * 4096);
        #pragma unroll
        for (int si = 0; si < 2; ++si) {
            int s = 2 * t + si;
            int dt = s >> 6, ln = s & 63;
            int l16 = ln & 15, quad = ln >> 4;
            int base = (dt * 16 + l16) * 17 + quad * 4;
            dst[s] = make_uint4(sL[base], sL[base + 1], sL[base + 2], sL[base + 3]);
        }
        if (t < 128) {                           // per-tile vmean partial, 1 atomic/dim
            float ssum = 0.f;
            #pragma unroll
            for (int j = 0; j < 16; ++j) {
                unsigned u = sL[t * 17 + j];
                ssum += __uint_as_float(u << 16);
                ssum += __uint_as_float(u & 0xffff0000u);
            }
            atomicAdd(&vsum[b * DIM + t], ssum);
        }
    }
}

// =================== attn_p: pipelined frag-major flash attention ===================
// Block = 256 thr = 4 waves = 1 q-tile (16 rows) x 4 key-slices. Grid = 8*128.
// launch_bounds(256,2): 256-VGPR cap so all 16 operand frags + next-K prefetch
// stay in registers (R6's 48-VGPR serialization and R7's 128-cap spill both avoided).
#define LOADK(kb_, KF_)                                                        \
    {                                                                          \
        const unsigned short* kT_ = kwB + (size_t)((kb_) >> 5) * 4096 + lane * 8; \
        _Pragma("unroll")                                                      \
        for (int f_ = 0; f_ < 8; ++f_) KF_[f_] = *(const short8*)(kT_ + f_ * 512); \
    }

#define CHUNK(KF_, kb_)                                                        \
    {                                                                          \
        /* V frags issue first: in flight during QK */                         \
        short8 VF[8];                                                          \
        {                                                                      \
            const unsigned short* vT_ = vwB + (size_t)((kb_) >> 5) * 4096 + lane * 8; \
            _Pragma("unroll")                                                  \
            for (int dt = 0; dt < 8; ++dt) VF[dt] = *(const short8*)(vT_ + dt * 512); \
        }                                                                      \
        floatx4 S0 = (floatx4){0.f, 0.f, 0.f, 0.f};                            \
        floatx4 S1 = (floatx4){0.f, 0.f, 0.f, 0.f};                            \
        _Pragma("unroll")                                                      \
        for (int ds = 0; ds < 4; ++ds)                                         \
            S0 = __builtin_amdgcn_mfma_f32_16x16x32_bf16(KF_[ds], Qf[ds], S0, 0, 0, 0); \
        _Pragma("unroll")                                                      \
        for (int ds = 0; ds < 4; ++ds)                                         \
            S1 = __builtin_amdgcn_mfma_f32_16x16x32_bf16(KF_[4 + ds], Qf[ds], S1, 0, 0, 0); \
        PREFETCH_NEXT                                                          \
        int kl0 = (kb_) + quad * 4;                                            \
        int kl1 = kl0 + 16;                                                    \
        float s0v[4], s1v[4];                                                  \
        float mt = m;                                                          \
        _Pragma("unroll")                                                      \
        for (int r = 0; r < 4; ++r) {                                          \
            s0v[r] = (kl0 + r < kend) ? S0[r] : NEGINF;                        \
            s1v[r] = (kl1 + r < kend) ? S1[r] : NEGINF;                        \
            mt = fmaxf(mt, fmaxf(s0v[r], s1v[r]));                             \
        }                                                                      \
        mt = fmaxf(mt, __shfl_xor(mt, 16));                                    \
        mt = fmaxf(mt, __shfl_xor(mt, 32));                                    \
        float alpha = __expf(m - mt);                                          \
        m = mt;                                                                \
        float p0[4], p1[4], ps = 0.f;                                          \
        _Pragma("unroll")                                                      \
        for (int r = 0; r < 4; ++r) {                                          \
            p0[r] = __expf(s0v[r] - mt);                                       \
            p1[r] = __expf(s1v[r] - mt);                                       \
            ps += p0[r] + p1[r];                                               \
        }                                                                      \
        ps += __shfl_xor(ps, 16);                                              \
        ps += __shfl_xor(ps, 32);                                              \
        l = l * alpha + ps;                                                    \
        _Pragma("unroll")                                                      \
        for (int dt = 0; dt < 8; ++dt) {                                       \
            _Pragma("unroll")                                                  \
            for (int r = 0; r < 4; ++r) O[dt][r] *= alpha;                     \
        }                                                                      \
        {                                                                      \
            uint2 w0, w1;                                                      \
            w0.x = pk_bf(p0[0], p0[1]); w0.y = pk_bf(p0[2], p0[3]);            \
            w1.x = pk_bf(p1[0], p1[1]); w1.y = pk_bf(p1[2], p1[3]);            \
            *(uint2*)&sPw[l16 * PSTR + quad * 4]      = w0;                    \
            *(uint2*)&sPw[l16 * PSTR + 16 + quad * 4] = w1;                    \
        }                                                                      \
        short8 Pf = *(const short8*)&sPw[l16 * PSTR + quad * 8];               \
        _Pragma("unroll")                                                      \
        for (int dt = 0; dt < 8; ++dt)                                         \
            O[dt] = __builtin_amdgcn_mfma_f32_16x16x32_bf16(VF[dt], Pf, O[dt], 0, 0, 0); \
    }

__global__ __launch_bounds__(256, 2) void attn_p(const float* __restrict__ q,
                                                 const unsigned short* __restrict__ kw,
                                                 const unsigned short* __restrict__ vw,
                                                 const int* __restrict__ lens,
                                                 const float* __restrict__ vsum,
                                                 float* __restrict__ out) {
    __shared__ __align__(16) unsigned short sP[4][16 * PSTR];  //  5120 B
    __shared__ float sC[3][16][132];                           // 25344 B
    __shared__ float sS[4][16][2];                             //   512 B

    int blk = blockIdx.x;
    int b = blk & 7;
    int q0 = (blk >> 3) * 16;
    int len = lens[b];
    int t = threadIdx.x;
    int lane = t & 63;
    int ks = t >> 6;                 // key-slice 0..3
    int l16 = lane & 15;
    int quad = lane >> 4;
    const int bo = b * SEQ * DIM;

    if (q0 >= len) {                 // block-uniform early exit: vmean rows
        int row = t >> 4;
        int c0 = (t & 15) * 8;
        float4 a = *(const float4*)&vsum[b * DIM + c0];
        float4 c = *(const float4*)&vsum[b * DIM + c0 + 4];
        float* op = out + bo + (q0 + row) * DIM + c0;
        *(float4*)op = make_float4(a.x * INVSEQ, a.y * INVSEQ, a.z * INVSEQ, a.w * INVSEQ);
        *(float4*)(op + 4) = make_float4(c.x * INVSEQ, c.y * INVSEQ, c.z * INVSEQ, c.w * INVSEQ);
        return;
    }

    int slice = ((len + 127) >> 7) << 5;   // 32-aligned per-wave key range
    int kbeg = ks * slice;
    int kend = min(kbeg + slice, len);

    floatx4 O[8];
    #pragma unroll
    for (int dt = 0; dt < 8; ++dt) O[dt] = (floatx4){0.f, 0.f, 0.f, 0.f};
    float m = NEGINF, l = 0.f;
    unsigned short* sPw = sP[ks];
    const unsigned short* kwB = kw + (size_t)b * 64 * 4096;
    const unsigned short* vwB = vw + (size_t)b * 64 * 4096;

    if (kbeg < kend) {
        short8 Qf[4];                // Q B-frags: B[k=d][n=qrow=l16]
        {
            const float* qp = q + bo + (q0 + l16) * DIM + quad * 8;
            #pragma unroll
            for (int ds = 0; ds < 4; ++ds) {
                float4 x0 = *(const float4*)(qp + ds * 32);
                float4 x1 = *(const float4*)(qp + ds * 32 + 4);
                U8 f;
                f.u[0] = pk_bf(x0.x, x0.y); f.u[1] = pk_bf(x0.z, x0.w);
                f.u[2] = pk_bf(x1.x, x1.y); f.u[3] = pk_bf(x1.z, x1.w);
                Qf[ds] = f.s;
            }
        }

        short8 KA[8], KB[8];
        LOADK(kbeg, KA)
        int kb = kbeg;
        while (true) {
#define PREFETCH_NEXT if (kb + 32 < kend) LOADK(kb + 32, KB)
            CHUNK(KA, kb)
#undef PREFETCH_NEXT
            kb += 32;
            if (kb >= kend) break;
#define PREFETCH_NEXT if (kb + 32 < kend) LOADK(kb + 32, KA)
            CHUNK(KB, kb)
#undef PREFETCH_NEXT
            kb += 32;
            if (kb >= kend) break;
        }
    }

    // ---- cross-slice combine ----
    if (ks > 0) {
        if (quad == 0) { sS[ks][l16][0] = m; sS[ks][l16][1] = l; }
        #pragma unroll
        for (int dt = 0; dt < 8; ++dt)
            *(floatx4*)&sC[ks - 1][l16][dt * 16 + quad * 4] = O[dt];
    }
    __syncthreads();

    if (ks == 0) {
        float mw[3], lw[3];
        float mstar = m;
        #pragma unroll
        for (int w = 0; w < 3; ++w) {
            mw[w] = sS[w + 1][l16][0];
            lw[w] = sS[w + 1][l16][1];
            mstar = fmaxf(mstar, mw[w]);
        }
        float s0 = __expf(m - mstar);
        float sw[3];
        float lstar = s0 * l;
        #pragma unroll
        for (int w = 0; w < 3; ++w) {
            sw[w] = __expf(mw[w] - mstar);
            lstar += sw[w] * lw[w];
        }
        float inv = 1.f / lstar;
        bool rowvalid = (q0 + l16) < len;
        float* ob = out + bo + (q0 + l16) * DIM;
        const float* vm = vsum + b * DIM;
        #pragma unroll
        for (int dt = 0; dt < 8; ++dt) {
            floatx4 acc = O[dt];
            #pragma unroll
            for (int r = 0; r < 4; ++r) acc[r] *= s0;
            #pragma unroll
            for (int w = 0; w < 3; ++w) {
                floatx4 ow = *(const floatx4*)&sC[w][l16][dt * 16 + quad * 4];
                #pragma unroll
                for (int r = 0; r < 4; ++r) acc[r] += sw[w] * ow[r];
            }
            float4 res;
            if (rowvalid) {
                res = make_float4(acc[0] * inv, acc[1] * inv, acc[2] * inv, acc[3] * inv);
            } else {
                float4 vv = *(const float4*)(vm + dt * 16 + quad * 4);
                res = make_float4(vv.x * INVSEQ, vv.y * INVSEQ, vv.z * INVSEQ, vv.w * INVSEQ);
            }
            *(float4*)(ob + dt * 16 + quad * 4) = res;
        }
    }
}

// =================== fallback path (ws too small): R3 kernel ===================
__global__ __launch_bounds__(256) void vmean_partial(const float* __restrict__ v,
                                                     float* __restrict__ part) {
    int blk = blockIdx.x;
    int b = blk >> 3, oct = blk & 7;
    int t = threadIdx.x;
    int d4 = t & 31, rg = t >> 5;
    const float4* vb = (const float4*)(v + (size_t)b * SEQ * DIM);
    float4 acc = make_float4(0.f, 0.f, 0.f, 0.f);
    int base = oct * 256 + rg * 32;
    #pragma unroll 8
    for (int i = 0; i < 32; ++i) {
        float4 x = vb[(size_t)(base + i) * 32 + d4];
        acc.x += x.x; acc.y += x.y; acc.z += x.z; acc.w += x.w;
    }
    __shared__ float4 red[8][32];
    red[rg][d4] = acc;
    __syncthreads();
    if (t < 32) {
        float4 s = red[0][t];
        #pragma unroll
        for (int r = 1; r < 8; ++r) {
            float4 x = red[r][t];
            s.x += x.x; s.y += x.y; s.z += x.z; s.w += x.w;
        }
        ((float4*)part)[(size_t)blk * 32 + t] = s;
    }
}

__global__ __launch_bounds__(128) void vmean_combine(const float* __restrict__ part,
                                                     float* __restrict__ vmean) {
    int b = blockIdx.x, t = threadIdx.x;
    float s = 0.f;
    #pragma unroll
    for (int o = 0; o < 8; ++o) s += part[((size_t)b * 8 + o) * DIM + t];
    vmean[b * DIM + t] = s * INVSEQ;
}

__global__ __launch_bounds__(512, 4) void attn_flash(const float* __restrict__ q,
                                                     const float* __restrict__ k,
                                                     const float* __restrict__ v,
                                                     const int* __restrict__ lens,
                                                     const float* __restrict__ vmean,
                                                     float* __restrict__ out) {
    __shared__ unsigned short sPf[8 * 16 * PSTR];
    __shared__ float sC[2][3][16][132];
    __shared__ float sS[2][4][16][2];

    int blk = blockIdx.x;
    int b = blk & 7;
    int g = blk >> 3;
    int q0 = g * 32;
    int len = lens[b];
    int t = threadIdx.x;
    int lane = t & 63;
    int wave = t >> 6;
    int qt = wave & 1;
    int ks = wave >> 1;
    int l16 = lane & 15;
    int quad = lane >> 4;
    const int bo = b * SEQ * DIM;

    int rowbase = q0 + qt * 16;
    bool active = q0 < len;

    int slice = (len + 3) >> 2;
    int kbeg = ks * slice;
    int kend = min(kbeg + slice, len);

    floatx4 O[8];
    #pragma unroll
    for (int dt = 0; dt < 8; ++dt) O[dt] = (floatx4){0.f, 0.f, 0.f, 0.f};
    float m = NEGINF, l = 0.f;
    unsigned short* sPw = &sPf[wave * 16 * PSTR];

    if (active && kbeg < kend) {
        short8 Qf[4];
        {
            const float* qp = q + bo + (rowbase + l16) * DIM + quad * 8;
            #pragma unroll
            for (int ds = 0; ds < 4; ++ds) {
                float4 x0 = *(const float4*)(qp + ds * 32);
                float4 x1 = *(const float4*)(qp + ds * 32 + 4);
                U8 f;
                f.u[0] = pk_bf(x0.x, x0.y); f.u[1] = pk_bf(x0.z, x0.w);
                f.u[2] = pk_bf(x1.x, x1.y); f.u[3] = pk_bf(x1.z, x1.w);
                Qf[ds] = f.s;
            }
        }
        for (int kb = kbeg; kb < kend; kb += 32) {
            int kr0 = kb + l16;      kr0 = kr0 < SEQ ? kr0 : SEQ - 1;
            int kr1 = kb + 16 + l16; kr1 = kr1 < SEQ ? kr1 : SEQ - 1;
            const float* kp0 = k + bo + kr0 * DIM + quad * 8;
            const float* kp1 = k + bo + kr1 * DIM + quad * 8;
            floatx4 S0 = (floatx4){0.f, 0.f, 0.f, 0.f};
            floatx4 S1 = (floatx4){0.f, 0.f, 0.f, 0.f};
            #pragma unroll
            for (int ds = 0; ds < 4; ++ds) {
                float4 a0 = *(const float4*)(kp0 + ds * 32);
                float4 a1 = *(const float4*)(kp0 + ds * 32 + 4);
                U8 f;
                f.u[0] = pk_bf(a0.x, a0.y); f.u[1] = pk_bf(a0.z, a0.w);
                f.u[2] = pk_bf(a1.x, a1.y); f.u[3] = pk_bf(a1.z, a1.w);
                S0 = __builtin_amdgcn_mfma_f32_16x16x32_bf16(f.s, Qf[ds], S0, 0, 0, 0);
            }
            #pragma unroll
            for (int ds = 0; ds < 4; ++ds) {
                float4 a0 = *(const float4*)(kp1 + ds * 32);
                float4 a1 = *(const float4*)(kp1 + ds * 32 + 4);
                U8 f;
                f.u[0] = pk_bf(a0.x, a0.y); f.u[1] = pk_bf(a0.z, a0.w);
                f.u[2] = pk_bf(a1.x, a1.y); f.u[3] = pk_bf(a1.z, a1.w);
                S1 = __builtin_amdgcn_mfma_f32_16x16x32_bf16(f.s, Qf[ds], S1, 0, 0, 0);
            }
            int kl0 = kb + quad * 4;
            int kl1 = kb + 16 + quad * 4;
            float s0v[4], s1v[4];
            float mt = m;
            #pragma unroll
            for (int r = 0; r < 4; ++r) {
                s0v[r] = (kl0 + r < kend) ? S0[r] * SCALE : NEGINF;
                s1v[r] = (kl1 + r < kend) ? S1[r] * SCALE : NEGINF;
                mt = fmaxf(mt, fmaxf(s0v[r], s1v[r]));
            }
            mt = fmaxf(mt, __shfl_xor(mt, 16));
            mt = fmaxf(mt, __shfl_xor(mt, 32));
            float alpha = __expf(m - mt);
            m = mt;
            float p0[4], p1[4], ps = 0.f;
            #pragma unroll
            for (int r = 0; r < 4; ++r) {
                p0[r] = __expf(s0v[r] - mt);
                p1[r] = __expf(s1v[r] - mt);
                ps += p0[r] + p1[r];
            }
            ps += __shfl_xor(ps, 16);
            ps += __shfl_xor(ps, 32);
            l = l * alpha + ps;
            #pragma unroll
            for (int dt = 0; dt < 8; ++dt) {
                #pragma unroll
                for (int r = 0; r < 4; ++r) O[dt][r] *= alpha;
            }
            {
                uint2 w0, w1;
                w0.x = pk_bf(p0[0], p0[1]); w0.y = pk_bf(p0[2], p0[3]);
                w1.x = pk_bf(p1[0], p1[1]); w1.y = pk_bf(p1[2], p1[3]);
                *(uint2*)&sPw[l16 * PSTR + quad * 4]      = w0;
                *(uint2*)&sPw[l16 * PSTR + 16 + quad * 4] = w1;
            }
            short8 Pf = *(const short8*)&sPw[l16 * PSTR + quad * 8];
            int vro[8];
            #pragma unroll
            for (int jj = 0; jj < 8; ++jj) {
                int kk = kb + quad * 8 + jj;
                kk = kk < SEQ ? kk : SEQ - 1;
                vro[jj] = kk * DIM;
            }
            const float* vb = v + bo + l16;
            #pragma unroll
            for (int dt = 0; dt < 8; ++dt) {
                int c = dt * 16;
                float x0 = vb[vro[0] + c], x1 = vb[vro[1] + c];
                float x2 = vb[vro[2] + c], x3 = vb[vro[3] + c];
                float x4 = vb[vro[4] + c], x5 = vb[vro[5] + c];
                float x6 = vb[vro[6] + c], x7 = vb[vro[7] + c];
                U8 f;
                f.u[0] = pk_bf(x0, x1); f.u[1] = pk_bf(x2, x3);
                f.u[2] = pk_bf(x4, x5); f.u[3] = pk_bf(x6, x7);
                O[dt] = __builtin_amdgcn_mfma_f32_16x16x32_bf16(f.s, Pf, O[dt], 0, 0, 0);
            }
        }
    }

    if (active && ks > 0) {
        if (quad == 0) { sS[qt][ks][l16][0] = m; sS[qt][ks][l16][1] = l; }
        #pragma unroll
        for (int dt = 0; dt < 8; ++dt)
            *(floatx4*)&sC[qt][ks - 1][l16][dt * 16 + quad * 4] = O[dt];
    }
    __syncthreads();

    if (ks == 0) {
        const float* vm = vmean + b * DIM;
        float* ob = out + bo + (rowbase + l16) * DIM;
        if (active) {
            float mw[3], lw[3];
            float mstar = m;
            #pragma unroll
            for (int w = 0; w < 3; ++w) {
                mw[w] = sS[qt][w + 1][l16][0];
                lw[w] = sS[qt][w + 1][l16][1];
                mstar = fmaxf(mstar, mw[w]);
            }
            float s0 = __expf(m - mstar);
            float sw[3];
            float lstar = s0 * l;
            #pragma unroll
            for (int w = 0; w < 3; ++w) {
                sw[w] = __expf(mw[w] - mstar);
                lstar += sw[w] * lw[w];
            }
            float inv = 1.f / lstar;
            bool rowvalid = (rowbase + l16) < len;
            #pragma unroll
            for (int dt = 0; dt < 8; ++dt) {
                floatx4 acc = O[dt];
                #pragma unroll
                for (int r = 0; r < 4; ++r) acc[r] *= s0;
                #pragma unroll
                for (int w = 0; w < 3; ++w) {
                    floatx4 ow = *(const floatx4*)&sC[qt][w][l16][dt * 16 + quad * 4];
                    #pragma unroll
                    for (int r = 0; r < 4; ++r) acc[r] += sw[w] * ow[r];
                }
                float4 res;
                if (rowvalid) {
                    res = make_float4(acc[0] * inv, acc[1] * inv, acc[2] * inv, acc[3] * inv);
                } else {
                    res = *(const float4*)(vm + dt * 16 + quad * 4);
                }
                *(float4*)(ob + dt * 16 + quad * 4) = res;
            }
        } else {
            #pragma unroll
            for (int dt = 0; dt < 8; ++dt)
                *(float4*)(ob + dt * 16 + quad * 4) =
                    *(const float4*)(vm + dt * 16 + quad * 4);
        }
    }
}

extern "C" void kernel_launch(void* const* d_in, const int* in_sizes, int n_in,
                              void* d_out, int out_size, void* d_ws, size_t ws_size,
                              hipStream_t stream) {
    const float* q = (const float*)d_in[0];
    const float* k = (const float*)d_in[1];
    const float* v = (const float*)d_in[2];
    const int* lens = (const int*)d_in[3];
    float* out = (float*)d_out;

    if (ws_size >= (size_t)WS_NEEDED) {
        float* vsum = (float*)((char*)d_ws + OFF_VSUM);
        unsigned short* kw = (unsigned short*)((char*)d_ws + OFF_KW);
        unsigned short* vw = (unsigned short*)((char*)d_ws + OFF_VW);
        hipMemsetAsync(vsum, 0, BATCH * DIM * sizeof(float), stream);
        conv3<<<dim3(1024), dim3(256), 0, stream>>>(k, v, kw, vw, vsum);
        attn_p<<<dim3(1024), dim3(256), 0, stream>>>(q, kw, vw, lens, vsum, out);
    } else {
        float* part = (float*)d_ws;
        float* vmean = part + 64 * DIM;
        vmean_partial<<<dim3(64), dim3(256), 0, stream>>>(v, part);
        vmean_combine<<<dim3(8), dim3(128), 0, stream>>>(part, vmean);
        attn_flash<<<dim3(512), dim3(512), 0, stream>>>(q, k, v, lens, vmean, out);
    }
}